// Round 1
// baseline (736.988 us; speedup 1.0000x reference)
//
#include <hip/hip_runtime.h>
#include <hip/hip_bf16.h>

typedef _Float16 f16;
typedef _Float16 f16x4 __attribute__((ext_vector_type(4)));
typedef _Float16 f16x8 __attribute__((ext_vector_type(8)));
typedef float f32x4 __attribute__((ext_vector_type(4)));

#define B_    64
#define T_    576
#define C_    1024
#define KDIM  576     // K for both GEMMs (GEMM2 zero-padded L..576)
#define MPAD  640     // 5 * 128 row tiles

// async global->LDS, 16B per lane; LDS dest must be linear (base + lane*16)
__device__ __forceinline__ void gload_lds16(const void* g, void* l) {
  __builtin_amdgcn_global_load_lds(
      (__attribute__((address_space(1))) void*)(void*)g,
      (__attribute__((address_space(3))) void*)l, 16, 0, 0);
}

// ---------------- DCT matrix generation (replicates jnp float32 op order) ----
__global__ void gen_mats(f16* __restrict__ Mh, f16* __restrict__ Ml,
                         f16* __restrict__ MiTh, f16* __restrict__ MiTl, int L) {
  int idx = blockIdx.x * 256 + threadIdx.x;
  if (idx >= MPAD * KDIM) return;
  int k = idx / KDIM;
  int t = idx - k * KDIM;
  const float pif = 3.14159265358979323846f;  // float32-rounded pi, as jnp does
  float v = 0.0f;
  if (blockIdx.y == 0) {
    // M[k][t] = s_k * cos(pi*(2t+1)*k / (2*576)); rows >=576 zero (M-pad)
    if (k < T_) {
      float a = pif * (float)(2 * t + 1);
      a = a * (float)k;
      a = a / 1152.0f;
      float s = (k == 0) ? sqrtf((float)(1.0 / 576.0)) : sqrtf((float)(2.0 / 576.0));
      v = s * cosf(a);
    }
    f16 h = (f16)v;
    Mh[idx] = h;
    Ml[idx] = (f16)(v - (float)h);
  } else {
    // MiT[k][l] = Mi[l][k] = s_l * cos(pi*(2k+1)*l / (2L)); zero outside LxL
    int l = t;
    if (k < L && l < L) {
      float a = pif * (float)(2 * k + 1);
      a = a * (float)l;
      a = a / (float)(2 * L);
      float s = (l == 0) ? sqrtf((float)(1.0 / (double)L))
                         : sqrtf((float)(2.0 / (double)L));
      v = s * cosf(a);
    }
    f16 h = (f16)v;
    MiTh[idx] = h;
    MiTl[idx] = (f16)(v - (float)h);
  }
}

// ---------------- transpose + fp32 -> fp16 hi/lo split ----------------------
// x[b][t][c] (f32) -> XTh/XTl[b][c][t] (f16)
__global__ void transpose_split(const float* __restrict__ x,
                                f16* __restrict__ XTh, f16* __restrict__ XTl) {
  __shared__ float tile[64][65];
  const int b = blockIdx.z;
  const int t0 = blockIdx.y * 64, c0 = blockIdx.x * 64;
  const int tx = threadIdx.x & 63, ty = threadIdx.x >> 6;
  const float* xp = x + ((size_t)b * T_ + t0) * C_ + c0;
#pragma unroll
  for (int j = 0; j < 16; ++j) {
    int tl = j * 4 + ty;
    tile[tl][tx] = xp[(size_t)tl * C_ + tx];
  }
  __syncthreads();
  const size_t obase = ((size_t)b * C_ + c0) * (size_t)T_ + t0;
#pragma unroll
  for (int j = 0; j < 16; ++j) {
    int cl = j * 4 + ty;
    float v = tile[tx][cl];
    f16 h = (f16)v;
    XTh[obase + (size_t)cl * T_ + tx] = h;
    XTl[obase + (size_t)cl * T_ + tx] = (f16)(v - (float)h);
  }
}

// ---------------- split-fp16 MFMA GEMM (m97-style 128x128 tile) -------------
// D[m][n] = sum_k A[m][k]*B[n][k]   (both operands row-major, K contiguous)
// STAGE 1: A=M[640][576], B=XT_b[1024][576]; epilogue -> trunc f32 + XdT hi/lo (transposed, zero-padded)
// STAGE 2: A=MiT[640][576], B=XdT_b[1024][576]; epilogue -> state (fp16-rounded, stored f32)
template <int STAGE>
__global__ void gemm_split(const f16* __restrict__ gAh, const f16* __restrict__ gAl,
                           const f16* __restrict__ gBh, const f16* __restrict__ gBl,
                           float* __restrict__ outp,
                           f16* __restrict__ XdTh, f16* __restrict__ XdTl, int L) {
  __shared__ __align__(16) f16 sAh[128 * 32];
  __shared__ __align__(16) f16 sAl[128 * 32];
  __shared__ __align__(16) f16 sBh[128 * 32];
  __shared__ __align__(16) f16 sBl[128 * 32];

  const int tid = threadIdx.x;
  const int lane = tid & 63, wid = tid >> 6;
  const int b = blockIdx.z, mt = blockIdx.y, nt = blockIdx.x;
  const int m0 = mt * 128, n0 = nt * 128;
  const int wr = wid >> 1, wc = wid & 1;
  const int l15 = lane & 15, lg = lane >> 4;

  const f16* bh = gBh + (size_t)b * C_ * KDIM;
  const f16* bl = gBl + (size_t)b * C_ * KDIM;

  f32x4 acc[4][4];
#pragma unroll
  for (int i = 0; i < 4; ++i)
#pragma unroll
    for (int j = 0; j < 4; ++j) acc[i][j] = (f32x4){0.f, 0.f, 0.f, 0.f};

  for (int kt = 0; kt < KDIM; kt += 32) {
    __syncthreads();
#pragma unroll
    for (int it = 0; it < 2; ++it) {
      const int o = it * 4096 + tid * 16;         // byte offset in 8KB tile
      const int r = o >> 6, cb = o & 63;          // row / byte-in-row (32 f16 = 64B)
      gload_lds16((const char*)gAh + ((size_t)(m0 + r) * KDIM + kt) * 2 + cb,
                  (char*)sAh + o);
      gload_lds16((const char*)gAl + ((size_t)(m0 + r) * KDIM + kt) * 2 + cb,
                  (char*)sAl + o);
      gload_lds16((const char*)bh + ((size_t)(n0 + r) * KDIM + kt) * 2 + cb,
                  (char*)sBh + o);
      gload_lds16((const char*)bl + ((size_t)(n0 + r) * KDIM + kt) * 2 + cb,
                  (char*)sBl + o);
    }
    __syncthreads();

    f16x8 ah[4], al[4], bhf[4], blf[4];
#pragma unroll
    for (int i = 0; i < 4; ++i) {
      const int ra = (wr * 64 + i * 16 + l15) * 32 + lg * 8;
      ah[i] = *(const f16x8*)&sAh[ra];
      al[i] = *(const f16x8*)&sAl[ra];
      const int rb = (wc * 64 + i * 16 + l15) * 32 + lg * 8;
      bhf[i] = *(const f16x8*)&sBh[rb];
      blf[i] = *(const f16x8*)&sBl[rb];
    }
#pragma unroll
    for (int i = 0; i < 4; ++i)
#pragma unroll
      for (int j = 0; j < 4; ++j) {
        acc[i][j] = __builtin_amdgcn_mfma_f32_16x16x32_f16(ah[i], bhf[j], acc[i][j], 0, 0, 0);
        acc[i][j] = __builtin_amdgcn_mfma_f32_16x16x32_f16(ah[i], blf[j], acc[i][j], 0, 0, 0);
        acc[i][j] = __builtin_amdgcn_mfma_f32_16x16x32_f16(al[i], bhf[j], acc[i][j], 0, 0, 0);
      }
  }

  // ---------------- epilogue ----------------
#pragma unroll
  for (int i = 0; i < 4; ++i) {
    const int k0 = m0 + wr * 64 + i * 16 + lg * 4;  // 4 consecutive output rows
#pragma unroll
    for (int j = 0; j < 4; ++j) {
      const int c = n0 + wc * 64 + j * 16 + l15;
      f32x4 v = acc[i][j];
      if constexpr (STAGE == 1) {
        f16x4 hv, lv;
#pragma unroll
        for (int r = 0; r < 4; ++r) {
          const int k = k0 + r;
          float val = (k < L) ? v[r] : 0.0f;
          if (k < L) outp[((size_t)b * L + k) * C_ + c] = val;  // x_dct_trunc f32
          f16 h = (f16)val;
          hv[r] = h;
          lv[r] = (f16)(val - (float)h);
        }
        if (k0 < KDIM) {  // transposed, zero-padded split for GEMM2's B operand
          *(f16x4*)&XdTh[((size_t)b * C_ + c) * KDIM + k0] = hv;
          *(f16x4*)&XdTl[((size_t)b * C_ + c) * KDIM + k0] = lv;
        }
      } else {
#pragma unroll
        for (int r = 0; r < 4; ++r) {
          const int k = k0 + r;
          if (k < L) {
            float sv = (float)(f16)v[r];  // fp16 RTNE rounding like .astype(float16)
            outp[((size_t)b * L + k) * C_ + c] = sv;
          }
        }
      }
    }
  }
}

// ---------------- launch ----------------------------------------------------
extern "C" void kernel_launch(void* const* d_in, const int* in_sizes, int n_in,
                              void* d_out, int out_size, void* d_ws, size_t ws_size,
                              hipStream_t stream) {
  (void)in_sizes; (void)n_in;
  const float* x = (const float*)d_in[0];

  // out = [state (64,L,1024) fp16-rounded | x_dct_trunc (64,L,1024) f32], both as f32
  const int L = out_size / (2 * B_ * C_);
  float* out_state = (float*)d_out;
  float* out_trunc = out_state + (size_t)B_ * L * C_;

  char* w = (char*)d_ws;
  const size_t SZ_XT = (size_t)B_ * C_ * KDIM * sizeof(f16);  // 75,497,472 B
  const size_t SZ_M  = (size_t)MPAD * KDIM * sizeof(f16);     //    737,280 B
  if (ws_size < 4 * SZ_XT + 4 * SZ_M) return;  // need ~305 MB scratch

  f16* XTh  = (f16*)(w);
  f16* XTl  = (f16*)(w + SZ_XT);
  f16* XdTh = (f16*)(w + 2 * SZ_XT);
  f16* XdTl = (f16*)(w + 3 * SZ_XT);
  f16* Mh   = (f16*)(w + 4 * SZ_XT);
  f16* Ml   = (f16*)(w + 4 * SZ_XT + SZ_M);
  f16* MiTh = (f16*)(w + 4 * SZ_XT + 2 * SZ_M);
  f16* MiTl = (f16*)(w + 4 * SZ_XT + 3 * SZ_M);

  gen_mats<<<dim3((MPAD * KDIM + 255) / 256, 2), 256, 0, stream>>>(Mh, Ml, MiTh, MiTl, L);
  transpose_split<<<dim3(C_ / 64, T_ / 64, B_), 256, 0, stream>>>(x, XTh, XTl);
  gemm_split<1><<<dim3(C_ / 128, MPAD / 128, B_), 256, 0, stream>>>(
      Mh, Ml, XTh, XTl, out_trunc, XdTh, XdTl, L);
  gemm_split<2><<<dim3(C_ / 128, MPAD / 128, B_), 256, 0, stream>>>(
      MiTh, MiTl, XdTh, XdTl, out_state, nullptr, nullptr, L);
}

// Round 3
// 546.643 us; speedup vs baseline: 1.3482x; 1.3482x over previous
//
#include <hip/hip_runtime.h>
#include <hip/hip_bf16.h>

typedef _Float16 f16;
typedef _Float16 f16x4 __attribute__((ext_vector_type(4)));
typedef _Float16 f16x8 __attribute__((ext_vector_type(8)));
typedef float f32x4 __attribute__((ext_vector_type(4)));

#define B_    64
#define T_    576
#define C_    1024
#define KDIM  576     // row stride of matrix / XT / XdT buffers
#define MPAD  640     // padded M rows for matrices

// async global->LDS, 16B per lane; LDS dest must be linear (base + lane*16)
__device__ __forceinline__ void gload_lds16(const void* g, void* l) {
  __builtin_amdgcn_global_load_lds(
      (__attribute__((address_space(1))) void*)(void*)g,
      (__attribute__((address_space(3))) void*)l, 16, 0, 0);
}

// ---------------- DCT matrix generation (replicates jnp float32 op order) ----
__global__ void gen_mats(f16* __restrict__ Mh, f16* __restrict__ MiTh, int L) {
  int idx = blockIdx.x * 256 + threadIdx.x;
  if (idx >= MPAD * KDIM) return;
  int k = idx / KDIM;
  int t = idx - k * KDIM;
  const float pif = 3.14159265358979323846f;  // f32-rounded pi, as jnp uses
  float v = 0.0f;
  if (blockIdx.y == 0) {
    // M[k][t] = s_k * cos(pi*(2t+1)*k / (2*576)); rows >=576 zero
    if (k < T_) {
      float a = pif * (float)(2 * t + 1);
      a = a * (float)k;
      a = a / 1152.0f;
      float s = (k == 0) ? sqrtf((float)(1.0 / 576.0)) : sqrtf((float)(2.0 / 576.0));
      v = s * cosf(a);
    }
    Mh[idx] = (f16)v;
  } else {
    // MiT[k][l] = Mi[l][k] = s_l * cos(pi*(2k+1)*l / (2L)); zero outside LxL
    int l = t;
    if (k < L && l < L) {
      float a = pif * (float)(2 * k + 1);
      a = a * (float)l;
      a = a / (float)(2 * L);
      float s = (l == 0) ? sqrtf((float)(1.0 / (double)L))
                         : sqrtf((float)(2.0 / (double)L));
      v = s * cosf(a);
    }
    MiTh[idx] = (f16)v;
  }
}

// ---------------- transpose + fp32 -> fp16 ----------------------------------
// x[b][t][c] (f32) -> XTh[b][c][t] (f16)
__global__ void transpose_f16(const float* __restrict__ x, f16* __restrict__ XTh) {
  __shared__ float tile[64][65];
  const int b = blockIdx.z;
  const int t0 = blockIdx.y * 64, c0 = blockIdx.x * 64;
  const int i = threadIdx.x;
  const float* xp = x + ((size_t)b * T_ + t0) * C_ + c0;
  const int lrow = i >> 4, lcq = (i & 15) * 4;
#pragma unroll
  for (int p = 0; p < 4; ++p) {
    int r = p * 16 + lrow;
    float4 v = *(const float4*)&xp[(size_t)r * C_ + lcq];
    tile[r][lcq + 0] = v.x; tile[r][lcq + 1] = v.y;
    tile[r][lcq + 2] = v.z; tile[r][lcq + 3] = v.w;
  }
  __syncthreads();
  const int tg = (i & 7) * 8, cl = i >> 3;  // cl in [0,32)
#pragma unroll
  for (int h = 0; h < 2; ++h) {
    int c = cl + h * 32;
    f16x8 o;
#pragma unroll
    for (int u = 0; u < 8; ++u) o[u] = (f16)tile[tg + u][c];
    *(f16x8*)&XTh[((size_t)b * C_ + c0 + c) * T_ + t0 + tg] = o;
  }
}

// ---------------- f16 MFMA GEMM (m97-style 128x128 tile) --------------------
// D[m][n] = sum_k A[m][k]*B[n][k]  (both row-major, K contiguous, stride KDIM)
// STAGE 1: A=M[640][576], B=XT_b[1024][576], kloop=576
//          epilogue: trunc rows k<L (f32) + XdT[b][c][k] f16 zero-padded k<Kpad
// STAGE 2: A=MiT[640][576], B=XdT_b[1024][576], kloop=Kpad
//          epilogue: state rows k<L (fp16-rounded, stored f32)
template <int STAGE>
__global__ void gemm_f16(const f16* __restrict__ gA, const f16* __restrict__ gB,
                         float* __restrict__ outp, f16* __restrict__ XdTh,
                         int L, int Kpad, int kloop) {
  __shared__ __align__(16) f16 sA[128 * 32];
  __shared__ __align__(16) f16 sB[128 * 32];

  const int tid = threadIdx.x;
  const int lane = tid & 63, wid = tid >> 6;
  const int b = blockIdx.z, mt = blockIdx.y, nt = blockIdx.x;
  const int m0 = mt * 128, n0 = nt * 128;
  const int wr = wid >> 1, wc = wid & 1;
  const int l15 = lane & 15, lg = lane >> 4;

  const f16* bb = gB + (size_t)b * C_ * KDIM;

  f32x4 acc[4][4];
#pragma unroll
  for (int i = 0; i < 4; ++i)
#pragma unroll
    for (int j = 0; j < 4; ++j) acc[i][j] = (f32x4){0.f, 0.f, 0.f, 0.f};

  for (int kt = 0; kt < kloop; kt += 32) {
    __syncthreads();
#pragma unroll
    for (int it = 0; it < 2; ++it) {
      const int o = it * 4096 + tid * 16;  // byte offset in 8KB tile
      const int r = o >> 6, cb = o & 63;   // row / byte-in-row (32 f16 = 64B)
      gload_lds16((const char*)gA + ((size_t)(m0 + r) * KDIM + kt) * 2 + cb,
                  (char*)sA + o);
      gload_lds16((const char*)bb + ((size_t)(n0 + r) * KDIM + kt) * 2 + cb,
                  (char*)sB + o);
    }
    __syncthreads();

    f16x8 af[4], bf[4];
#pragma unroll
    for (int i = 0; i < 4; ++i) {
      af[i] = *(const f16x8*)&sA[(wr * 64 + i * 16 + l15) * 32 + lg * 8];
      bf[i] = *(const f16x8*)&sB[(wc * 64 + i * 16 + l15) * 32 + lg * 8];
    }
#pragma unroll
    for (int i = 0; i < 4; ++i)
#pragma unroll
      for (int j = 0; j < 4; ++j)
        acc[i][j] = __builtin_amdgcn_mfma_f32_16x16x32_f16(af[i], bf[j], acc[i][j], 0, 0, 0);
  }

  // ---------------- epilogue ----------------
#pragma unroll
  for (int i = 0; i < 4; ++i) {
    const int k0 = m0 + wr * 64 + i * 16 + lg * 4;  // 4 consecutive output rows
#pragma unroll
    for (int j = 0; j < 4; ++j) {
      const int c = n0 + wc * 64 + j * 16 + l15;
      f32x4 v = acc[i][j];
      if constexpr (STAGE == 1) {
        f16x4 hv;
#pragma unroll
        for (int r = 0; r < 4; ++r) {
          const int k = k0 + r;
          float val = (k < L) ? v[r] : 0.0f;
          if (k < L) outp[((size_t)b * L + k) * C_ + c] = val;  // x_dct_trunc
          hv[r] = (f16)val;
        }
        if (k0 < Kpad)  // transposed, zero-padded f16 copy for GEMM2's B
          *(f16x4*)&XdTh[((size_t)b * C_ + c) * KDIM + k0] = hv;
      } else {
#pragma unroll
        for (int r = 0; r < 4; ++r) {
          const int k = k0 + r;
          if (k < L)
            outp[((size_t)b * L + k) * C_ + c] = (float)(f16)v[r];  // fp16 RTNE
        }
      }
    }
  }
}

// ---------------- launch ----------------------------------------------------
extern "C" void kernel_launch(void* const* d_in, const int* in_sizes, int n_in,
                              void* d_out, int out_size, void* d_ws, size_t ws_size,
                              hipStream_t stream) {
  (void)in_sizes; (void)n_in;
  const float* x = (const float*)d_in[0];

  // out = [state (64,L,1024) fp16-rounded | x_dct_trunc (64,L,1024)], both f32
  const int L = out_size / (2 * B_ * C_);
  const int Kpad = ((L + 31) / 32) * 32;          // GEMM2 K extent, 32-aligned
  const int mtiles = (Kpad + 127) / 128;          // M tiles actually needed
  float* out_state = (float*)d_out;
  float* out_trunc = out_state + (size_t)B_ * L * C_;

  char* w = (char*)d_ws;
  const size_t SZ_XT = (size_t)B_ * C_ * KDIM * sizeof(f16);  // 75,497,472 B
  const size_t SZ_M  = (size_t)MPAD * KDIM * sizeof(f16);     //    737,280 B
  if (ws_size < 2 * SZ_XT + 2 * SZ_M) return;  // ~153 MB scratch

  f16* XTh  = (f16*)(w);
  f16* XdTh = (f16*)(w + SZ_XT);
  f16* Mh   = (f16*)(w + 2 * SZ_XT);
  f16* MiTh = (f16*)(w + 2 * SZ_XT + SZ_M);

  gen_mats<<<dim3((MPAD * KDIM + 255) / 256, 2), 256, 0, stream>>>(Mh, MiTh, L);
  transpose_f16<<<dim3(C_ / 64, T_ / 64, B_), 256, 0, stream>>>(x, XTh);
  gemm_f16<1><<<dim3(C_ / 128, mtiles, B_), 256, 0, stream>>>(
      Mh, XTh, out_trunc, XdTh, L, Kpad, KDIM);
  gemm_f16<2><<<dim3(C_ / 128, mtiles, B_), 256, 0, stream>>>(
      MiTh, XdTh, out_state, nullptr, L, Kpad, Kpad);
}

// Round 4
// 530.740 us; speedup vs baseline: 1.3886x; 1.0300x over previous
//
#include <hip/hip_runtime.h>
#include <hip/hip_bf16.h>

typedef _Float16 f16;
typedef _Float16 f16x4 __attribute__((ext_vector_type(4)));
typedef _Float16 f16x8 __attribute__((ext_vector_type(8)));
typedef float f32x4 __attribute__((ext_vector_type(4)));

#define B_    64
#define T_    576
#define C_    1024
#define KDIM  576     // K extent / row stride of all staged matrices
#define MPAD  640     // padded row count for matrix buffers

// async global->LDS, 16B per lane; LDS dest must be linear (base + lane*16)
__device__ __forceinline__ void gload_lds16(const void* g, void* l) {
  __builtin_amdgcn_global_load_lds(
      (__attribute__((address_space(1))) void*)(void*)g,
      (__attribute__((address_space(3))) void*)l, 16, 0, 0);
}

// ---------------- matrix generation (replicates jnp float32 op order) -------
// y=0: Mh  [640][576]  = M[k][t]   f16            (zero rows k>=576)
// y=1: MT  [640][576]  = M[l][t] at [t][l], hi/lo (zero rows t>=576)
// y=2: MiT [640][576]  = Mi[l][k] at [k][l], hi/lo (zero outside k<L,l<L)
__global__ void gen_mats(f16* __restrict__ Mh,
                         f16* __restrict__ MTh, f16* __restrict__ MTl,
                         f16* __restrict__ MiTh, f16* __restrict__ MiTl, int L) {
  int idx = blockIdx.x * 256 + threadIdx.x;
  if (idx >= MPAD * KDIM) return;
  int row = idx / KDIM;
  int col = idx - row * KDIM;
  const float pif = 3.14159265358979323846f;  // f32-rounded pi, as jnp uses
  float v = 0.0f;
  if (blockIdx.y == 0) {
    // M[k][t], k=row, t=col
    if (row < T_) {
      float a = pif * (float)(2 * col + 1);
      a = a * (float)row;
      a = a / 1152.0f;
      float s = (row == 0) ? sqrtf((float)(1.0 / 576.0)) : sqrtf((float)(2.0 / 576.0));
      v = s * cosf(a);
    }
    Mh[idx] = (f16)v;
  } else if (blockIdx.y == 1) {
    // MT[t][l] = M[l][t], t=row, l=col
    if (row < T_) {
      float a = pif * (float)(2 * row + 1);
      a = a * (float)col;
      a = a / 1152.0f;
      float s = (col == 0) ? sqrtf((float)(1.0 / 576.0)) : sqrtf((float)(2.0 / 576.0));
      v = s * cosf(a);
    }
    f16 h = (f16)v;
    MTh[idx] = h;
    MTl[idx] = (f16)(v - (float)h);
  } else {
    // MiT[k][l] = Mi[l][k], k=row, l=col; dct_mat(L)
    if (row < L && col < L) {
      float a = pif * (float)(2 * row + 1);
      a = a * (float)col;
      a = a / (float)(2 * L);
      float s = (col == 0) ? sqrtf((float)(1.0 / (double)L))
                           : sqrtf((float)(2.0 / (double)L));
      v = s * cosf(a);
    }
    f16 h = (f16)v;
    MiTh[idx] = h;
    MiTl[idx] = (f16)(v - (float)h);
  }
}

// ---------------- G = MiT . M_L  via hi/lo split MFMA (f32-accurate) --------
// D[m=t][n=k] = sum_l MT[t][l]*MiT[k][l]  ->  store G[k][t] f16 (t contiguous)
__global__ void gemm_G(const f16* __restrict__ gAh, const f16* __restrict__ gAl,
                       const f16* __restrict__ gBh, const f16* __restrict__ gBl,
                       f16* __restrict__ G) {
  __shared__ __align__(16) f16 sAh[128 * 32];
  __shared__ __align__(16) f16 sAl[128 * 32];
  __shared__ __align__(16) f16 sBh[128 * 32];
  __shared__ __align__(16) f16 sBl[128 * 32];
  const int tid = threadIdx.x, lane = tid & 63, wid = tid >> 6;
  const int m0 = blockIdx.y * 128, n0 = blockIdx.x * 128;
  const int wr = wid >> 1, wc = wid & 1;
  const int l15 = lane & 15, lg = lane >> 4;

  f32x4 acc[4][4];
#pragma unroll
  for (int i = 0; i < 4; ++i)
#pragma unroll
    for (int j = 0; j < 4; ++j) acc[i][j] = (f32x4){0.f, 0.f, 0.f, 0.f};

  for (int kt = 0; kt < KDIM; kt += 32) {
    __syncthreads();
#pragma unroll
    for (int it = 0; it < 2; ++it) {
      const int o = it * 4096 + tid * 16;
      const int r = o >> 6, cb = o & 63;
      gload_lds16((const char*)gAh + ((size_t)(m0 + r) * KDIM + kt) * 2 + cb, (char*)sAh + o);
      gload_lds16((const char*)gAl + ((size_t)(m0 + r) * KDIM + kt) * 2 + cb, (char*)sAl + o);
      gload_lds16((const char*)gBh + ((size_t)(n0 + r) * KDIM + kt) * 2 + cb, (char*)sBh + o);
      gload_lds16((const char*)gBl + ((size_t)(n0 + r) * KDIM + kt) * 2 + cb, (char*)sBl + o);
    }
    __syncthreads();

    f16x8 ah[4], al[4], bh[4], bl[4];
#pragma unroll
    for (int i = 0; i < 4; ++i) {
      const int ra = (wr * 64 + i * 16 + l15) * 32 + lg * 8;
      ah[i] = *(const f16x8*)&sAh[ra];
      al[i] = *(const f16x8*)&sAl[ra];
      const int rb = (wc * 64 + i * 16 + l15) * 32 + lg * 8;
      bh[i] = *(const f16x8*)&sBh[rb];
      bl[i] = *(const f16x8*)&sBl[rb];
    }
#pragma unroll
    for (int i = 0; i < 4; ++i)
#pragma unroll
      for (int j = 0; j < 4; ++j) {
        acc[i][j] = __builtin_amdgcn_mfma_f32_16x16x32_f16(ah[i], bh[j], acc[i][j], 0, 0, 0);
        acc[i][j] = __builtin_amdgcn_mfma_f32_16x16x32_f16(ah[i], bl[j], acc[i][j], 0, 0, 0);
        acc[i][j] = __builtin_amdgcn_mfma_f32_16x16x32_f16(al[i], bh[j], acc[i][j], 0, 0, 0);
      }
  }

#pragma unroll
  for (int i = 0; i < 4; ++i) {
    const int t4 = m0 + wr * 64 + i * 16 + lg * 4;  // 4 consecutive t
#pragma unroll
    for (int j = 0; j < 4; ++j) {
      const int k = n0 + wc * 64 + j * 16 + l15;
      if (t4 < T_) {  // t4..t4+3 all < 576 (t4 multiple of 4)
        f32x4 v = acc[i][j];
        f16x4 hv;
#pragma unroll
        for (int r = 0; r < 4; ++r) hv[r] = (f16)v[r];
        *(f16x4*)&G[(size_t)k * KDIM + t4] = hv;
      }
    }
  }
}

// ---------------- transpose + fp32 -> fp16 ----------------------------------
// x[b][t][c] (f32) -> XT[b][c][t] (f16)
__global__ void transpose_f16(const float* __restrict__ x, f16* __restrict__ XT) {
  __shared__ float tile[64][65];
  const int b = blockIdx.z;
  const int t0 = blockIdx.y * 64, c0 = blockIdx.x * 64;
  const int i = threadIdx.x;
  const float* xp = x + ((size_t)b * T_ + t0) * C_ + c0;
  const int lrow = i >> 4, lcq = (i & 15) * 4;
#pragma unroll
  for (int p = 0; p < 4; ++p) {
    int r = p * 16 + lrow;
    float4 v = *(const float4*)&xp[(size_t)r * C_ + lcq];
    tile[r][lcq + 0] = v.x; tile[r][lcq + 1] = v.y;
    tile[r][lcq + 2] = v.z; tile[r][lcq + 3] = v.w;
  }
  __syncthreads();
  const int tg = (i & 7) * 8, cl = i >> 3;  // cl in [0,32)
#pragma unroll
  for (int h = 0; h < 2; ++h) {
    int c = cl + h * 32;
    f16x8 o;
#pragma unroll
    for (int u = 0; u < 8; ++u) o[u] = (f16)tile[tg + u][c];
    *(f16x8*)&XT[((size_t)b * C_ + c0 + c) * T_ + t0 + tg] = o;
  }
}

// ---------------- merged main GEMM (m97-style 128x128 tile) -----------------
// z = 2*b + stage.  stage0: trunc = M . x   stage1: state = G . x
// D[m=k][n=c] = sum_t A[k][t] * XT_b[c][t]
__global__ void gemm_main(const f16* __restrict__ gM, const f16* __restrict__ gG,
                          const f16* __restrict__ gXT,
                          float* __restrict__ out_trunc, float* __restrict__ out_state,
                          int L) {
  __shared__ __align__(16) f16 sA[128 * 32];
  __shared__ __align__(16) f16 sB[128 * 32];

  const int tid = threadIdx.x, lane = tid & 63, wid = tid >> 6;
  const int z = blockIdx.z, b = z >> 1, stage = z & 1;
  const int m0 = blockIdx.y * 128, n0 = blockIdx.x * 128;
  const int wr = wid >> 1, wc = wid & 1;
  const int l15 = lane & 15, lg = lane >> 4;

  const f16* gA = stage ? gG : gM;
  const f16* bb = gXT + (size_t)b * C_ * KDIM;

  f32x4 acc[4][4];
#pragma unroll
  for (int i = 0; i < 4; ++i)
#pragma unroll
    for (int j = 0; j < 4; ++j) acc[i][j] = (f32x4){0.f, 0.f, 0.f, 0.f};

  for (int kt = 0; kt < KDIM; kt += 32) {
    __syncthreads();
#pragma unroll
    for (int it = 0; it < 2; ++it) {
      const int o = it * 4096 + tid * 16;  // byte offset in 8KB tile
      const int r = o >> 6, cb = o & 63;   // row / byte-in-row (32 f16 = 64B)
      gload_lds16((const char*)gA + ((size_t)(m0 + r) * KDIM + kt) * 2 + cb,
                  (char*)sA + o);
      gload_lds16((const char*)bb + ((size_t)(n0 + r) * KDIM + kt) * 2 + cb,
                  (char*)sB + o);
    }
    __syncthreads();

    f16x8 af[4], bf[4];
#pragma unroll
    for (int i = 0; i < 4; ++i) {
      af[i] = *(const f16x8*)&sA[(wr * 64 + i * 16 + l15) * 32 + lg * 8];
      bf[i] = *(const f16x8*)&sB[(wc * 64 + i * 16 + l15) * 32 + lg * 8];
    }
#pragma unroll
    for (int i = 0; i < 4; ++i)
#pragma unroll
      for (int j = 0; j < 4; ++j)
        acc[i][j] = __builtin_amdgcn_mfma_f32_16x16x32_f16(af[i], bf[j], acc[i][j], 0, 0, 0);
  }

  float* outp = stage ? out_state : out_trunc;
#pragma unroll
  for (int i = 0; i < 4; ++i) {
    const int k0 = m0 + wr * 64 + i * 16 + lg * 4;  // 4 consecutive output rows
#pragma unroll
    for (int j = 0; j < 4; ++j) {
      const int c = n0 + wc * 64 + j * 16 + l15;
      f32x4 v = acc[i][j];
#pragma unroll
      for (int r = 0; r < 4; ++r) {
        const int k = k0 + r;
        if (k < L) {
          float val = v[r];
          if (stage) val = (float)(f16)val;  // fp16 RTNE like .astype(float16)
          outp[((size_t)b * L + k) * C_ + c] = val;
        }
      }
    }
  }
}

// ---------------- launch ----------------------------------------------------
extern "C" void kernel_launch(void* const* d_in, const int* in_sizes, int n_in,
                              void* d_out, int out_size, void* d_ws, size_t ws_size,
                              hipStream_t stream) {
  (void)in_sizes; (void)n_in;
  const float* x = (const float*)d_in[0];

  // out = [state (64,L,1024) fp16-rounded | x_dct_trunc (64,L,1024)], both f32
  const int L = out_size / (2 * B_ * C_);
  const int mtiles = (L + 127) / 128;
  float* out_state = (float*)d_out;
  float* out_trunc = out_state + (size_t)B_ * L * C_;

  char* w = (char*)d_ws;
  const size_t SZ_XT = (size_t)B_ * C_ * KDIM * sizeof(f16);  // 75,497,472 B
  const size_t SZ_M  = (size_t)MPAD * KDIM * sizeof(f16);     //    737,280 B
  if (ws_size < SZ_XT + 6 * SZ_M) return;  // ~80 MB scratch

  f16* XT   = (f16*)(w);
  f16* Mh   = (f16*)(w + SZ_XT);
  f16* Gh   = (f16*)(w + SZ_XT + 1 * SZ_M);
  f16* MTh  = (f16*)(w + SZ_XT + 2 * SZ_M);
  f16* MTl  = (f16*)(w + SZ_XT + 3 * SZ_M);
  f16* MiTh = (f16*)(w + SZ_XT + 4 * SZ_M);
  f16* MiTl = (f16*)(w + SZ_XT + 5 * SZ_M);

  gen_mats<<<dim3((MPAD * KDIM + 255) / 256, 3), 256, 0, stream>>>(
      Mh, MTh, MTl, MiTh, MiTl, L);
  gemm_G<<<dim3(MPAD / 128, MPAD / 128), 256, 0, stream>>>(
      MTh, MTl, MiTh, MiTl, Gh);
  transpose_f16<<<dim3(C_ / 64, T_ / 64, B_), 256, 0, stream>>>(x, XT);
  gemm_main<<<dim3(C_ / 128, mtiles, 2 * B_), 256, 0, stream>>>(
      Mh, Gh, XT, out_trunc, out_state, L);
}